// Round 1
// baseline (162.421 us; speedup 1.0000x reference)
//
#include <hip/hip_runtime.h>
#include <stdint.h>

#define S      56
#define NC     20
#define NCELL  (S*S)          // 3136
#define NBOXES (NCELL*2)      // 6272
#define DIM    94080
#define BD1    62720          // NCELL*NC
#define BD2    68992          // BD1 + NCELL*2
#define CAND   256
#define MAXOUT 30
#define NTHR   1024
#define NWAVE  16
#define NBIN   8192
#define CAP    512
#define K1THR  256

// ---------------------------------------------------------------------------
// Shared decode: per-cell score/class -> two 64-bit sort keys.
// key = (score_bits << 18) | ((8191-idx) << 5) | cls  — score desc, idx asc.
// Bit-exact copy of the previously verified in-kernel decode.
// ---------------------------------------------------------------------------
__device__ __forceinline__ void decode_cell(const float* __restrict__ img, int cell,
                                            uint64_t& k0, uint64_t& k1) {
#pragma clang fp contract(off)
    const float4* pv = (const float4*)(img + cell * NC);
    float p[NC];
    #pragma unroll
    for (int q = 0; q < 5; q++) {
        float4 v = pv[q];
        p[4*q+0] = v.x; p[4*q+1] = v.y; p[4*q+2] = v.z; p[4*q+3] = v.w;
    }
    float2 cf = *(const float2*)(img + BD1 + cell * 2);
    uint64_t kk[2];
    #pragma unroll
    for (int bb = 0; bb < 2; bb++) {
        float conf = bb ? cf.y : cf.x;
        float best = conf * p[0];   // rn product; first-occurrence argmax
        int   cls  = 0;
        #pragma unroll
        for (int c = 1; c < NC; c++) {
            float v = conf * p[c];
            if (v > best) { best = v; cls = c; }
        }
        uint32_t sb = (best >= 0.1f) ? __float_as_uint(best) : 0u;
        int idx = cell * 2 + bb;
        kk[bb] = ((uint64_t)sb << 18) | ((uint64_t)(8191 - idx) << 5) | (uint64_t)cls;
    }
    k0 = kk[0]; k1 = kk[1];
}

// ---------------------------------------------------------------------------
// Kernel 1: full-GPU decode. 3328 blocks x 256 thr, HBM-bound, no serial tail.
// ---------------------------------------------------------------------------
__global__ __launch_bounds__(K1THR) void decode_kernel(const float* __restrict__ in,
                                                       uint64_t* __restrict__ keys) {
#pragma clang fp contract(off)
    const int cell = blockIdx.x * K1THR + threadIdx.x;
    const int b    = blockIdx.y;
    if (cell >= NCELL) return;
    const float* img = in + (size_t)b * DIM;
    uint64_t k0, k1;
    decode_cell(img, cell, k0, k1);
    ulonglong2 st; st.x = k0; st.y = k1;
    *(ulonglong2*)(keys + (size_t)b * NBOXES + (size_t)cell * 2) = st;   // 16B coalesced
}

// ---------------------------------------------------------------------------
// Kernel 2: per-image select + sort + NMS. FROMKEYS=true loads precomputed
// keys (50 KB/img, coalesced); FROMKEYS=false is the old monolithic fallback.
// ---------------------------------------------------------------------------
template<bool FROMKEYS>
__global__ __launch_bounds__(NTHR) void det_kernel(const float* __restrict__ in,
                                                   const uint64_t* __restrict__ keys,
                                                   float* __restrict__ out) {
#pragma clang fp contract(off)
    const int b    = blockIdx.x;
    const int tid  = threadIdx.x;
    const int lane = tid & 63;
    const int wv   = tid >> 6;
    const float* img = in + (size_t)b * DIM;

    __shared__ uint32_t hist[NBIN];          // 32 KB
    __shared__ uint32_t wsum[NWAVE];
    __shared__ int      bstar_s;
    __shared__ int      nsel;
    __shared__ uint64_t skey[CAP];           // 4 KB
    __shared__ uint64_t ssort[CAND];         // 2 KB
    __shared__ float cymin[CAND], cxmin[CAND], cymax[CAND], cxmax[CAND];
    __shared__ float carea[CAND], cscore[CAND], ccls[CAND];
    __shared__ int   klist[MAXOUT];
    __shared__ float rowbuf[MAXOUT * 6];

    // ---------- zero histogram + init ----------
    ((uint4*)hist)[tid]        = uint4{0,0,0,0};
    ((uint4*)hist)[tid + NTHR] = uint4{0,0,0,0};
    if (tid == 0) nsel = 0;
    if (tid < MAXOUT) klist[tid] = -1;

    // ---------- Phase 1: obtain keys (load precomputed, or decode inline) ----
    uint64_t key[4][2];
    bool     vld[4];
    const uint64_t* kb = FROMKEYS ? (keys + (size_t)b * NBOXES) : nullptr;
    #pragma unroll
    for (int i = 0; i < 4; i++) {
        int cell = tid + NTHR * i;
        vld[i] = (cell < NCELL);
        key[i][0] = key[i][1] = 0;
        if (vld[i]) {
            if (FROMKEYS) {
                ulonglong2 v = *(const ulonglong2*)(kb + (size_t)cell * 2);
                key[i][0] = v.x; key[i][1] = v.y;
            } else {
                decode_cell(img, cell, key[i][0], key[i][1]);
            }
        }
    }
    __syncthreads();   // B1: hist zeroed everywhere

    // ---------- Phase 2a: single histogram pass (bin = score_bits >> 17) ----------
    #pragma unroll
    for (int i = 0; i < 4; i++) {
        #pragma unroll
        for (int bb = 0; bb < 2; bb++) {
            uint32_t sb = (uint32_t)(key[i][bb] >> 18);
            if (vld[i] && sb != 0u) atomicAdd(&hist[sb >> 17], 1u);
            unsigned long long zm = __ballot(vld[i] && sb == 0u);
            if (lane == 0 && zm) atomicAdd(&hist[0], (uint32_t)__popcll(zm));
        }
    }
    __syncthreads();   // B2

    // ---------- Phase 2b: block suffix-scan -> threshold bin b* ----------
    uint4 h0 = ((const uint4*)hist)[2*tid];
    uint4 h1 = ((const uint4*)hist)[2*tid+1];
    uint32_t hsum = h0.x+h0.y+h0.z+h0.w + h1.x+h1.y+h1.z+h1.w;
    uint32_t v = hsum;
    #pragma unroll
    for (int off = 1; off < 64; off <<= 1) {
        uint32_t u = __shfl_down(v, off);
        if (lane + off < 64) v += u;
    }
    if (lane == 0) wsum[wv] = v;
    __syncthreads();   // B3
    uint32_t add = 0;
    for (int w = wv + 1; w < NWAVE; w++) add += wsum[w];
    uint32_t Sm    = v + add;       // elems in bins >= 8*tid
    uint32_t above = Sm - hsum;     // elems in bins >= 8*(tid+1)
    if (above < CAND && CAND <= Sm) {   // exactly one thread
        uint32_t hh[8] = {h1.w, h1.z, h1.y, h1.x, h0.w, h0.z, h0.y, h0.x};
        uint32_t g = above;
        int bsel = 8 * tid;
        #pragma unroll
        for (int j = 0; j < 8; j++) {
            if (g + hh[j] >= CAND) { bsel = 8 * tid + (7 - j); break; }
            g += hh[j];
        }
        bstar_s = bsel;
    }
    __syncthreads();   // B4
    const uint32_t bstar = (uint32_t)bstar_s;

    // ---------- Phase 2c: compact superset (bin >= b*), wave-aggregated ----------
    #pragma unroll
    for (int i = 0; i < 4; i++) {
        #pragma unroll
        for (int bb = 0; bb < 2; bb++) {
            bool pred = vld[i] && ((uint32_t)(key[i][bb] >> 35) >= bstar);
            unsigned long long mask = __ballot(pred);
            if (mask) {
                int leader = __ffsll(mask) - 1;
                int base = 0;
                if (lane == leader) base = atomicAdd(&nsel, (int)__popcll(mask));
                base = __shfl(base, leader);
                if (pred) {
                    int pos = base + (int)__popcll(mask & ((1ull << lane) - 1ull));
                    if (pos < CAP) skey[pos] = key[i][bb];
                }
            }
        }
    }
    __syncthreads();   // B5

    // ---------- Phase 3: rank-sort top-256 of the M-superset ----------
    const int M = (nsel < CAP) ? nsel : CAP;
    if (tid < M) {
        uint64_t my = skey[tid];
        int r = 0;
        #pragma unroll 4
        for (int j = 0; j < M; j++) r += (skey[j] > my);   // broadcast LDS reads
        if (r < CAND) ssort[r] = my;
    }
    __syncthreads();   // B6

    // ---------- Phase 4: decode the 256 candidate boxes ----------
    if (tid < CAND) {
        uint64_t k = ssort[tid];
        int idx      = 8191 - (int)((k >> 5) & 0x1FFF);
        int cls      = (int)(k & 31u);
        uint32_t sb  = (uint32_t)(k >> 18);
        int cell = idx >> 1, bb = idx & 1;
        int i = cell / S, j = cell - i * S;   // i = row (y), j = col (x)
        float4 co = *(const float4*)(img + BD2 + cell * 8 + bb * 4);
        float x  = (co.x + (float)j) / 56.0f;
        float y  = (co.y + (float)i) / 56.0f;
        float wx = co.z * co.z;
        float wy = co.w * co.w;
        float hx = wx * 0.5f, hy = wy * 0.5f;
        float xmin = x - hx, ymin = y - hy, xmax = x + hx, ymax = y + hy;
        cymin[tid] = ymin; cxmin[tid] = xmin; cymax[tid] = ymax; cxmax[tid] = xmax;
        carea[tid] = fmaxf(ymax - ymin, 0.0f) * fmaxf(xmax - xmin, 0.0f);
        cscore[tid] = __uint_as_float(sb);
        ccls[tid]   = (float)cls;
    }
    __syncthreads();   // B7

    // ---------- Phase 5: single-wave greedy NMS (lane owns 4 consecutive) ----------
    if (wv == 0) {
        float bym[4], bxm[4], byM[4], bxM[4], bar[4];
        #pragma unroll
        for (int s = 0; s < 4; s++) {
            int c = 4 * lane + s;
            bym[s] = cymin[c]; bxm[s] = cxmin[c];
            byM[s] = cymax[c]; bxM[s] = cxmax[c]; bar[s] = carea[c];
        }
        unsigned vmask = 0xFu;
        for (int it = 0; it < MAXOUT; it++) {
            unsigned long long mk = __ballot(vmask != 0u);
            if (!mk) break;
            int l0 = __ffsll(mk) - 1;
            int vb = __shfl((int)vmask, l0);
            int p  = 4 * l0 + (__ffs(vb) - 1);   // first valid candidate overall
            if (lane == 0) klist[it] = p;
            float pym = cymin[p], pxm = cxmin[p];
            float pyM = cymax[p], pxM = cxmax[p], par = carea[p];
            #pragma unroll
            for (int s = 0; s < 4; s++) {
                int c = 4 * lane + s;
                float iy = fmaxf(0.0f, fminf(pyM, byM[s]) - fmaxf(pym, bym[s]));
                float ix = fmaxf(0.0f, fminf(pxM, bxM[s]) - fmaxf(pxm, bxm[s]));
                float inter = iy * ix;
                float uni   = par + bar[s] - inter;
                float iou   = (uni > 0.0f) ? (inter / uni) : 0.0f;  // exact IEEE div
                if (c == p || !(iou <= 0.4f)) vmask &= ~(1u << s);
            }
        }
    }
    __syncthreads();   // B8

    // ---------- Phase 6: emit 30x6 rows ----------
    if (tid < MAXOUT) {
        int p = klist[tid];
        float* r = &rowbuf[tid * 6];
        if (p >= 0) {
            r[0] = cymin[p]; r[1] = cxmin[p]; r[2] = cymax[p];
            r[3] = cxmax[p]; r[4] = cscore[p]; r[5] = ccls[p];
        } else {
            r[0] = r[1] = r[2] = r[3] = r[4] = r[5] = 0.0f;
        }
    }
    __syncthreads();   // B9
    float* ob = out + (size_t)b * (MAXOUT * 6);
    if (tid < MAXOUT * 6) ob[tid] = rowbuf[tid];
}

extern "C" void kernel_launch(void* const* d_in, const int* in_sizes, int n_in,
                              void* d_out, int out_size, void* d_ws, size_t ws_size,
                              hipStream_t stream) {
    const float* in  = (const float*)d_in[0];
    float*       out = (float*)d_out;
    const int B = in_sizes[0] / DIM;   // 256
    const size_t keys_bytes = (size_t)B * NBOXES * sizeof(uint64_t);   // 12.85 MB

    if (d_ws != nullptr && ws_size >= keys_bytes) {
        uint64_t* keys = (uint64_t*)d_ws;
        decode_kernel<<<dim3((NCELL + K1THR - 1) / K1THR, B), dim3(K1THR), 0, stream>>>(in, keys);
        det_kernel<true><<<dim3(B), dim3(NTHR), 0, stream>>>(in, keys, out);
    } else {
        // fallback: old monolithic path (no workspace dependency)
        det_kernel<false><<<dim3(B), dim3(NTHR), 0, stream>>>(in, nullptr, out);
    }
}